// Round 2
// baseline (115.422 us; speedup 1.0000x reference)
//
#include <hip/hip_runtime.h>

// ---------------------------------------------------------------------------
// QNNClassifier: 2-qubit StronglyEntanglingLayers + <Z0> + Linear(1,1)
// ev = psi0^T * Re(U^H D U) * psi0 with psi0 real => batch-shared 4x4 real
// symmetric quadratic form. FUSED: thread 0 of each block rebuilds the form
// in LDS (~300 serial instrs, overlapped across blocks); all threads stream.
// Single dispatch: 16 MiB in, 8 MiB out => ~4 us roofline.
// ---------------------------------------------------------------------------

struct C2 { float re, im; };
__device__ inline C2 cmul(C2 a, C2 b) { return {a.re*b.re - a.im*b.im, a.re*b.im + a.im*b.re}; }
__device__ inline C2 cadd(C2 a, C2 b) { return {a.re + b.re, a.im + b.im}; }

// Build A = fc_w * Re(U^H D U) (16 floats) and b into sA[0..16].
__device__ void qnn_build_form(const float* __restrict__ qp,
                               const float* __restrict__ fc_w,
                               const float* __restrict__ fc_b,
                               float* __restrict__ sA) {
    C2 U[4][4];
    for (int i = 0; i < 4; i++)
        for (int j = 0; j < 4; j++)
            U[i][j] = { (i == j) ? 1.f : 0.f, 0.f };

    for (int l = 0; l < 2; l++) {
        C2 r[2][2][2];  // [wire][row][col]
        for (int w = 0; w < 2; w++) {
            float phi = qp[(l*2 + w)*3 + 0];
            float th  = qp[(l*2 + w)*3 + 1];
            float om  = qp[(l*2 + w)*3 + 2];
            float c = cosf(0.5f * th), s = sinf(0.5f * th);
            float ap = -0.5f * (phi + om);   // ep = e^{i*ap}
            float am =  0.5f * (phi - om);   // em = e^{i*am}
            C2 ep = { cosf(ap), sinf(ap) };
            C2 em = { cosf(am), sinf(am) };
            r[w][0][0] = {  ep.re * c,  ep.im * c };
            r[w][0][1] = { -em.re * s, -em.im * s };
            r[w][1][0] = {  em.re * s, -em.im * s };   // conj(em)*s
            r[w][1][1] = {  ep.re * c, -ep.im * c };   // conj(ep)*c
        }
        // Un = kron(r0, r1) @ U
        C2 Un[4][4];
        for (int a = 0; a < 2; a++)
            for (int b = 0; b < 2; b++) {
                int i = 2*a + b;
                for (int j = 0; j < 4; j++) {
                    C2 acc = {0.f, 0.f};
                    for (int c = 0; c < 2; c++)
                        for (int d = 0; d < 2; d++) {
                            int k = 2*c + d;
                            C2 kij = cmul(r[0][a][c], r[1][b][d]);
                            acc = cadd(acc, cmul(kij, U[k][j]));
                        }
                    Un[i][j] = acc;
                }
            }
        // CNOT01: swap rows 2,3.  CNOT10: swap rows 1,3.
        for (int j = 0; j < 4; j++) { C2 t = Un[2][j]; Un[2][j] = Un[3][j]; Un[3][j] = t; }
        for (int j = 0; j < 4; j++) { C2 t = Un[1][j]; Un[1][j] = Un[3][j]; Un[3][j] = t; }
        for (int i = 0; i < 4; i++)
            for (int j = 0; j < 4; j++)
                U[i][j] = Un[i][j];
    }

    float w0 = fc_w[0];
    // A[i][j] = Re( sum_k conj(U[k][i]) * D[k] * U[k][j] ), D = (+1,+1,-1,-1)
    for (int i = 0; i < 4; i++)
        for (int j = 0; j < 4; j++) {
            float acc = 0.f;
            for (int k = 0; k < 4; k++) {
                float d = (k < 2) ? 1.f : -1.f;
                acc += d * (U[k][i].re * U[k][j].re + U[k][i].im * U[k][j].im);
            }
            sA[i*4 + j] = w0 * acc;   // fold fc_w into A
        }
    sA[16] = fc_b[0];
}

__global__ __launch_bounds__(256) void qnn_fused_kernel(
        const float4* __restrict__ x,       // [B/2] float4 == [B,2] floats
        const float* __restrict__ qp,       // [2,2,3]
        const float* __restrict__ fc_w,     // [1,1]
        const float* __restrict__ fc_b,     // [1]
        float4* __restrict__ out,           // [B/4] float4 == [B] floats
        int n4) {                           // B/4
    __shared__ float sA[17];
    if (threadIdx.x == 0)
        qnn_build_form(qp, fc_w, fc_b, sA);
    __syncthreads();

    float A[16];
#pragma unroll
    for (int i = 0; i < 16; i++) A[i] = sA[i];   // same addr all lanes -> broadcast
    float b = sA[16];

    int t = blockIdx.x * blockDim.x + threadIdx.x;
    if (t >= n4) return;

    float4 xa = x[2*t];
    float4 xb = x[2*t + 1];
    float xs[8] = { xa.x, xa.y, xa.z, xa.w, xb.x, xb.y, xb.z, xb.w };

    float oo[4];
#pragma unroll
    for (int e = 0; e < 4; e++) {
        float s0, c0, s1, c1;
        __sincosf(0.5f * xs[2*e],     &s0, &c0);
        __sincosf(0.5f * xs[2*e + 1], &s1, &c1);
        float v0 = c0*c1, v1 = c0*s1, v2 = s0*c1, v3 = s0*s1;
        float ev = v0*(A[0]*v0  + A[1]*v1  + A[2]*v2  + A[3]*v3)
                 + v1*(A[4]*v0  + A[5]*v1  + A[6]*v2  + A[7]*v3)
                 + v2*(A[8]*v0  + A[9]*v1  + A[10]*v2 + A[11]*v3)
                 + v3*(A[12]*v0 + A[13]*v1 + A[14]*v2 + A[15]*v3);
        oo[e] = ev + b;
    }
    out[t] = make_float4(oo[0], oo[1], oo[2], oo[3]);
}

extern "C" void kernel_launch(void* const* d_in, const int* in_sizes, int n_in,
                              void* d_out, int out_size, void* d_ws, size_t ws_size,
                              hipStream_t stream) {
    const float* x    = (const float*)d_in[0];   // [B, 2] float32
    const float* qp   = (const float*)d_in[1];   // [2, 2, 3] float32
    const float* fc_w = (const float*)d_in[2];   // [1, 1] float32
    const float* fc_b = (const float*)d_in[3];   // [1] float32
    float* out = (float*)d_out;                  // [B, 1] float32

    int n  = in_sizes[0] / 2;   // batch size
    int n4 = n / 4;

    int block = 256;
    int grid = (n4 + block - 1) / block;
    qnn_fused_kernel<<<grid, block, 0, stream>>>(
        (const float4*)x, qp, fc_w, fc_b, (float4*)out, n4);
}

// Round 3
// 75.566 us; speedup vs baseline: 1.5274x; 1.5274x over previous
//
#include <hip/hip_runtime.h>

// ---------------------------------------------------------------------------
// QNNClassifier: 2-qubit StronglyEntanglingLayers + <Z0> + Linear(1,1)
// ev = psi0^T * Re(U^H D U) * psi0 with psi0 real => batch-shared 4x4 real
// symmetric quadratic form.
//
// R3 design: single dispatch, 1024 blocks (== resident capacity at 4
// blocks/CU with VGPR~104) so the redundant per-thread form rebuild runs in
// ONE concurrent round device-wide (~0.7us), then grid-stride streaming of
// 16.8 MiB in / 8.4 MiB out. No LDS, no __syncthreads (R2's per-block serial
// build x 8 sequential rounds was the 44.5us regression).
// ---------------------------------------------------------------------------

struct C2 { float re, im; };
__device__ inline C2 cmul(C2 a, C2 b) { return {a.re*b.re - a.im*b.im, a.re*b.im + a.im*b.re}; }
__device__ inline C2 cadd(C2 a, C2 b) { return {a.re + b.re, a.im + b.im}; }

// Build A = fc_w * Re(U^H D U) (16 floats) and b. Runs redundantly in every
// thread (SIMT: identical work across lanes costs the same as one lane).
__device__ inline void qnn_build_form(const float* __restrict__ qp,
                                      const float* __restrict__ fc_w,
                                      const float* __restrict__ fc_b,
                                      float* __restrict__ A, float* __restrict__ bout) {
    C2 U[4][4];
#pragma unroll
    for (int i = 0; i < 4; i++)
#pragma unroll
        for (int j = 0; j < 4; j++)
            U[i][j] = { (i == j) ? 1.f : 0.f, 0.f };

#pragma unroll
    for (int l = 0; l < 2; l++) {
        C2 r[2][2][2];  // [wire][row][col]
#pragma unroll
        for (int w = 0; w < 2; w++) {
            float phi = qp[(l*2 + w)*3 + 0];
            float th  = qp[(l*2 + w)*3 + 1];
            float om  = qp[(l*2 + w)*3 + 2];
            float c, s, epre, epim, emre, emim;
            __sincosf(0.5f * th, &s, &c);
            __sincosf(-0.5f * (phi + om), &epim, &epre);   // ep = e^{-i(phi+om)/2}
            __sincosf( 0.5f * (phi - om), &emim, &emre);   // em = e^{ i(phi-om)/2}
            r[w][0][0] = {  epre * c,  epim * c };
            r[w][0][1] = { -emre * s, -emim * s };
            r[w][1][0] = {  emre * s, -emim * s };   // conj(em)*s
            r[w][1][1] = {  epre * c, -epim * c };   // conj(ep)*c
        }
        // Un = kron(r0, r1) @ U
        C2 Un[4][4];
#pragma unroll
        for (int a = 0; a < 2; a++)
#pragma unroll
            for (int b = 0; b < 2; b++) {
                int i = 2*a + b;
#pragma unroll
                for (int j = 0; j < 4; j++) {
                    C2 acc = {0.f, 0.f};
#pragma unroll
                    for (int c = 0; c < 2; c++)
#pragma unroll
                        for (int d = 0; d < 2; d++) {
                            int k = 2*c + d;
                            C2 kij = cmul(r[0][a][c], r[1][b][d]);
                            acc = cadd(acc, cmul(kij, U[k][j]));
                        }
                    Un[i][j] = acc;
                }
            }
        // CNOT01: swap rows 2,3.  CNOT10: swap rows 1,3.
#pragma unroll
        for (int j = 0; j < 4; j++) { C2 t = Un[2][j]; Un[2][j] = Un[3][j]; Un[3][j] = t; }
#pragma unroll
        for (int j = 0; j < 4; j++) { C2 t = Un[1][j]; Un[1][j] = Un[3][j]; Un[3][j] = t; }
#pragma unroll
        for (int i = 0; i < 4; i++)
#pragma unroll
            for (int j = 0; j < 4; j++)
                U[i][j] = Un[i][j];
    }

    float w0 = fc_w[0];
    // A[i][j] = Re( sum_k conj(U[k][i]) * D[k] * U[k][j] ), D = (+1,+1,-1,-1)
#pragma unroll
    for (int i = 0; i < 4; i++)
#pragma unroll
        for (int j = 0; j < 4; j++) {
            float acc = 0.f;
#pragma unroll
            for (int k = 0; k < 4; k++) {
                float d = (k < 2) ? 1.f : -1.f;
                acc += d * (U[k][i].re * U[k][j].re + U[k][i].im * U[k][j].im);
            }
            A[i*4 + j] = w0 * acc;   // fold fc_w into A
        }
    *bout = fc_b[0];
}

__global__ __launch_bounds__(256) void qnn_fused_kernel(
        const float4* __restrict__ x,       // [B/2] float4 == [B,2] floats
        const float* __restrict__ qp,       // [2,2,3]
        const float* __restrict__ fc_w,     // [1,1]
        const float* __restrict__ fc_b,     // [1]
        float4* __restrict__ out,           // [B/4] float4 == [B] floats
        int n4) {                           // B/4
    float A[16], b;
    qnn_build_form(qp, fc_w, fc_b, A, &b);

    int stride = gridDim.x * blockDim.x;
    for (int t = blockIdx.x * blockDim.x + threadIdx.x; t < n4; t += stride) {
        float4 xa = x[2*t];
        float4 xb = x[2*t + 1];
        float xs[8] = { xa.x, xa.y, xa.z, xa.w, xb.x, xb.y, xb.z, xb.w };

        float oo[4];
#pragma unroll
        for (int e = 0; e < 4; e++) {
            float s0, c0, s1, c1;
            __sincosf(0.5f * xs[2*e],     &s0, &c0);
            __sincosf(0.5f * xs[2*e + 1], &s1, &c1);
            float v0 = c0*c1, v1 = c0*s1, v2 = s0*c1, v3 = s0*s1;
            float ev = v0*(A[0]*v0  + A[1]*v1  + A[2]*v2  + A[3]*v3)
                     + v1*(A[4]*v0  + A[5]*v1  + A[6]*v2  + A[7]*v3)
                     + v2*(A[8]*v0  + A[9]*v1  + A[10]*v2 + A[11]*v3)
                     + v3*(A[12]*v0 + A[13]*v1 + A[14]*v2 + A[15]*v3);
            oo[e] = ev + b;
        }
        out[t] = make_float4(oo[0], oo[1], oo[2], oo[3]);
    }
}

extern "C" void kernel_launch(void* const* d_in, const int* in_sizes, int n_in,
                              void* d_out, int out_size, void* d_ws, size_t ws_size,
                              hipStream_t stream) {
    const float* x    = (const float*)d_in[0];   // [B, 2] float32
    const float* qp   = (const float*)d_in[1];   // [2, 2, 3] float32
    const float* fc_w = (const float*)d_in[2];   // [1, 1] float32
    const float* fc_b = (const float*)d_in[3];   // [1] float32
    float* out = (float*)d_out;                  // [B, 1] float32

    int n  = in_sizes[0] / 2;   // batch size
    int n4 = n / 4;

    // 1024 blocks == one resident round at ~4 blocks/CU (VGPR-capped):
    // the redundant form rebuild costs one concurrent ~0.7us, not N rounds.
    int block = 256;
    int grid  = 1024;
    qnn_fused_kernel<<<grid, block, 0, stream>>>(
        (const float4*)x, qp, fc_w, fc_b, (float4*)out, n4);
}